// Round 5
// baseline (865.623 us; speedup 1.0000x reference)
//
#include <hip/hip_runtime.h>

#define HW 4096
#define CD 256
#define KB 32           /* keys per KV-iter */
#define NKB 32          /* 32 x 32 = 1024 keys per split */
#define NSP 4
#define C1 0.09016844f  /* (1/16) * log2(e) */

typedef __bf16 bf16x8v __attribute__((ext_vector_type(8)));
typedef float f32x4 __attribute__((ext_vector_type(4)));
typedef unsigned short u16;
typedef u16 u16x4 __attribute__((ext_vector_type(4)));
typedef u16 u16x8 __attribute__((ext_vector_type(8)));

static __device__ __forceinline__ u16 f2bf(float f){
  __bf16 h = (__bf16)f;
  return __builtin_bit_cast(u16, h);
}
static __device__ __forceinline__ float bf2f(u16 v){
  unsigned u = ((unsigned)v) << 16;
  return __builtin_bit_cast(float, u);
}

static __device__ __forceinline__ f32x4 MFMA(u16x8 a, u16x8 b, f32x4 c){
  return __builtin_amdgcn_mfma_f32_16x16x32_bf16(
      __builtin_bit_cast(bf16x8v, a), __builtin_bit_cast(bf16x8v, b), c, 0, 0, 0);
}

#define GLL16(gsrc, ldst) __builtin_amdgcn_global_load_lds( \
    (const __attribute__((address_space(1))) void*)(gsrc),  \
    (__attribute__((address_space(3))) void*)(ldst), 16, 0, 0)

// ---------------- kernel 0: weights fp32 -> bf16 (layout kept [out][in]) ----
__global__ void k_prep(const float* __restrict__ wq, const float* __restrict__ wk,
                       const float* __restrict__ wv, const float* __restrict__ wp,
                       u16* __restrict__ Wbf){
  int z = blockIdx.y;
  const float* src = (z==0)?wq:(z==1)?wk:(z==2)?wv:wp;
  int i = (blockIdx.x*256 + threadIdx.x)*4;
  float4 v = *(const float4*)(src + i);
  u16x4 o = { f2bf(v.x), f2bf(v.y), f2bf(v.z), f2bf(v.w) };
  *(u16x4*)(Wbf + z*65536 + i) = o;
}

// ---------------- kernel 1: groupnorm, write xn pixel-major bf16 ------------
__global__ void k_gn(const float* __restrict__ x, const float* __restrict__ gamma,
                     const float* __restrict__ beta, u16* __restrict__ xnT){
  int g = blockIdx.x, b = blockIdx.y;
  int tid = threadIdx.x;
  const float* xp = x + ((size_t)(b*CD) + g*32) * HW;
  float s0 = 0.f, s1 = 0.f;
  for (int i = tid*4; i < 32*HW; i += 1024){
    float4 v = *(const float4*)(xp + i);
    s0 += v.x + v.y + v.z + v.w;
    s1 += v.x*v.x + v.y*v.y + v.z*v.z + v.w*v.w;
  }
  #pragma unroll
  for (int m = 1; m < 64; m <<= 1){ s0 += __shfl_xor(s0, m); s1 += __shfl_xor(s1, m); }
  __shared__ float red[8];
  __shared__ float stats[2];
  int lane = tid & 63, wave = tid >> 6;
  if (lane == 0){ red[wave] = s0; red[4+wave] = s1; }
  __syncthreads();
  if (tid == 0){
    float t0 = red[0]+red[1]+red[2]+red[3];
    float t1 = red[4]+red[5]+red[6]+red[7];
    float inv_n = 1.0f/(32.0f*HW);
    float mean = t0*inv_n;
    float var = t1*inv_n - mean*mean;
    stats[0] = mean;
    stats[1] = rsqrtf(var + 1e-5f);
  }
  __syncthreads();
  float mean = stats[0], rstd = stats[1];
  int pl = tid >> 2, c8 = (tid & 3)*8;
  float av[8], bv_[8];
  #pragma unroll
  for (int e = 0; e < 8; ++e){
    int c = g*32 + c8 + e;
    float a = rstd * gamma[c];
    av[e] = a;
    bv_[e] = beta[c] - mean*a;
  }
  const float* xb = x + (size_t)(b*CD + g*32 + c8)*HW;
  for (int it = 0; it < 64; ++it){
    int p = it*64 + pl;
    u16x8 o;
    #pragma unroll
    for (int e = 0; e < 8; ++e){
      float v = xb[(size_t)e*HW + p];
      o[e] = f2bf(v*av[e] + bv_[e]);
    }
    *(u16x8*)(xnT + ((size_t)(b*HW) + p)*CD + g*32 + c8) = o;
  }
}

// ---------------- kernel 2: QKV projection GEMM -----------------------------
// Q,K pixel-major [b][p][c]; V channel-major [b][c][p]
__global__ __launch_bounds__(256,2) void k_qkv(const u16* __restrict__ xnT, const u16* __restrict__ Wbf,
    const float* __restrict__ bq, const float* __restrict__ bk, const float* __restrict__ bv,
    u16* __restrict__ Q, u16* __restrict__ K, u16* __restrict__ V){
  __shared__ u16 tile[4][4096];
  int z = blockIdx.z, b = blockIdx.y, pbase = blockIdx.x*64;
  int tid = threadIdx.x, lane = tid & 63, wave = tid >> 6;
  int lq = lane & 15, lg = lane >> 4;
  const u16* W = Wbf + z*65536;
  const float* bias = (z==0)?bq:(z==1)?bk:bv;
  int nbase = wave*64;
  f32x4 acc[4][4] = {};
  #pragma unroll
  for (int kk = 0; kk < 8; ++kk){
    u16x8 af[4], bf[4];
    #pragma unroll
    for (int m = 0; m < 4; ++m)
      af[m] = *(const u16x8*)(xnT + ((size_t)(b*HW + pbase + m*16 + lq))*CD + kk*32 + lg*8);
    #pragma unroll
    for (int n = 0; n < 4; ++n)
      bf[n] = *(const u16x8*)(W + (size_t)(nbase + n*16 + lq)*CD + kk*32 + lg*8);
    #pragma unroll
    for (int m = 0; m < 4; ++m)
      #pragma unroll
      for (int n = 0; n < 4; ++n)
        acc[m][n] = MFMA(af[m], bf[n], acc[m][n]);
  }
  #pragma unroll
  for (int n = 0; n < 4; ++n){
    float bb = bias[nbase + n*16 + lq];
    #pragma unroll
    for (int m = 0; m < 4; ++m){
      acc[m][n][0] += bb; acc[m][n][1] += bb; acc[m][n][2] += bb; acc[m][n][3] += bb;
    }
  }
  if (z == 2){
    #pragma unroll
    for (int m = 0; m < 4; ++m)
      #pragma unroll
      for (int n = 0; n < 4; ++n){
        int d = nbase + n*16 + lq;
        int p0 = pbase + m*16 + lg*4;
        u16x4 o = { f2bf(acc[m][n][0]), f2bf(acc[m][n][1]), f2bf(acc[m][n][2]), f2bf(acc[m][n][3]) };
        *(u16x4*)(V + (size_t)(b*CD + d)*HW + p0) = o;
      }
  } else {
    u16* dst = (z==0)?Q:K;
    u16* tl = tile[wave];
    #pragma unroll
    for (int m = 0; m < 4; ++m)
      #pragma unroll
      for (int n = 0; n < 4; ++n)
        #pragma unroll
        for (int r = 0; r < 4; ++r){
          int row = m*16 + lg*4 + r;
          int col = n*16 + lq;
          tl[row*64 + ((((col>>3) + row) & 7)<<3) + (col & 7)] = f2bf(acc[m][n][r]);
        }
    #pragma unroll
    for (int j = 0; j < 8; ++j){
      int idx = j*64 + lane;
      int row = idx >> 3, ch = idx & 7;
      u16x8 v = *(const u16x8*)(tl + row*64 + (((ch + row)&7)<<3));
      *(u16x8*)(dst + ((size_t)(b*HW + pbase + row))*CD + nbase + ch*8) = v;
    }
  }
}

// ---------------- kernel 3: flash attention (key-split 4) -------------------
// grid (32 qtiles, 4 splits, 4 batches) = 512 blocks = 2/CU; 4 waves x 32 q.
// LDS 72KB: K dbuf 2x16K | V dbuf 2x16K | P 4x2K (separate -> 1 barrier/iter).
// __launch_bounds__(256,2): total reg budget 256 (VGPR+AGPR unified). r1/r4
// lesson: plain 256-thr kernels got 256 arch VGPR + 128 AGPR = 384/wave ->
// only 1 wave/SIMD (occupancy 11.8% both rounds despite 144KB vs 64KB LDS).
// V/P use paired-row (128B) swizzle: KB=32 makes 64B rows -> 16-bank cover
// -> r4's 6.8M conflicts; pairing two d (or q) per row restores 32-bank cover.
__global__ __launch_bounds__(256,2) void k_attn(const u16* __restrict__ Q, const u16* __restrict__ K,
    const u16* __restrict__ V, u16* __restrict__ Opart, float2* __restrict__ ml){
  extern __shared__ char smem[];
  int tid = threadIdx.x, lane = tid & 63, wave = tid >> 6;
  int lq = lane & 15, lg = lane >> 4;
  int qt = blockIdx.x, sp = blockIdx.y, b = blockIdx.z;
  int qbase = qt*128 + wave*32;
  int key0 = sp*(NKB*KB);

  // staging source offsets (inverse of the LDS read swizzles; LDS dest linear)
  int ke[4], ve[4];
  #pragma unroll
  for (int i = 0; i < 4; ++i){
    int G = i*256 + tid;            // chunk 0..1023 of 16B per 16KB tile
    int kr = G >> 5;                // K row (32 rows x 512B)
    ke[i] = kr*CD + (((G & 31) ^ kr) & 31)*8;
    int vrow = G >> 3;              // V d-pair row (128 rows x 128B)
    int p = (G >> 2) & 1;           // d parity
    int j = ((G & 3) - vrow) & 3;   // stored k-chunk
    ve[i] = (vrow*2 + p)*HW + j*8;
  }
  // V/P read offset within a 128B paired row (constant per lane)
  int bvo = (lq>>1)*128 + (((lq&1)*4 + ((lg + (lq>>1)) & 3)))*16;

  u16x8 qa[2][8];
  #pragma unroll
  for (int mt = 0; mt < 2; ++mt)
    #pragma unroll
    for (int cc = 0; cc < 8; ++cc)
      qa[mt][cc] = *(const u16x8*)(Q + ((size_t)(b*HW + qbase + mt*16 + lq))*CD + cc*32 + lg*8);

  f32x4 o[2][16] = {};
  float m_[2][4], l_[2][4];
  #pragma unroll
  for (int mt = 0; mt < 2; ++mt)
    #pragma unroll
    for (int r = 0; r < 4; ++r){ m_[mt][r] = -3.0e38f; l_[mt][r] = 0.f; }

  const u16* Kb = K + (size_t)(b*HW + key0)*CD;
  const u16* Vb = V + (size_t)(b*CD)*HW + key0;
  char* Pw = smem + 65536 + wave*2048;

  {
    char* kd = smem; char* vd = smem + 32768;
    #pragma unroll
    for (int i = 0; i < 4; ++i){
      GLL16(Kb + ke[i], kd + i*4096 + wave*1024);
      GLL16(Vb + ve[i], vd + i*4096 + wave*1024);
    }
  }
  __syncthreads();
  int cur = 0;
  for (int kb = 0; kb < NKB; ++kb){
    if (kb + 1 < NKB){
      char* kd = smem + (cur^1)*16384;
      char* vd = smem + 32768 + (cur^1)*16384;
      const u16* kg = Kb + (size_t)(kb+1)*KB*CD;
      const u16* vg = Vb + (kb+1)*KB;
      #pragma unroll
      for (int i = 0; i < 4; ++i){
        GLL16(kg + ke[i], kd + i*4096 + wave*1024);
        GLL16(vg + ve[i], vd + i*4096 + wave*1024);
      }
    }
    const char* kt = smem + cur*16384;
    const char* vt = smem + 32768 + cur*16384;

    f32x4 sa[2][2];
    #pragma unroll
    for (int mt = 0; mt < 2; ++mt)
      #pragma unroll
      for (int nt = 0; nt < 2; ++nt)
        sa[mt][nt] = (f32x4){0.f,0.f,0.f,0.f};
    #pragma unroll
    for (int nt = 0; nt < 2; ++nt){
      int row = nt*16 + lq;
      #pragma unroll
      for (int cc = 0; cc < 8; ++cc){
        int ch = cc*4 + lg;
        u16x8 kf = *(const u16x8*)(kt + row*512 + (((ch ^ row) & 31) << 4));
        sa[0][nt] = MFMA(qa[0][cc], kf, sa[0][nt]);
        sa[1][nt] = MFMA(qa[1][cc], kf, sa[1][nt]);
      }
    }
    float mx[2][4];
    #pragma unroll
    for (int mt = 0; mt < 2; ++mt)
      #pragma unroll
      for (int r = 0; r < 4; ++r){
        float v = fmaxf(sa[mt][0][r], sa[mt][1][r]) * C1;
        v = fmaxf(v, __shfl_xor(v, 1));
        v = fmaxf(v, __shfl_xor(v, 2));
        v = fmaxf(v, __shfl_xor(v, 4));
        v = fmaxf(v, __shfl_xor(v, 8));
        mx[mt][r] = v;
      }
    int okf = 1;
    #pragma unroll
    for (int mt = 0; mt < 2; ++mt)
      #pragma unroll
      for (int r = 0; r < 4; ++r)
        okf &= (mx[mt][r] <= m_[mt][r] + 8.0f) ? 1 : 0;
    if (!__all(okf)){
      #pragma unroll
      for (int mt = 0; mt < 2; ++mt)
        #pragma unroll
        for (int r = 0; r < 4; ++r){
          float nm = fmaxf(m_[mt][r], mx[mt][r]);
          float corr = exp2f(m_[mt][r] - nm);
          m_[mt][r] = nm;
          l_[mt][r] *= corr;
          #pragma unroll
          for (int nf = 0; nf < 16; ++nf)
            o[mt][nf][r] *= corr;
        }
    }
    #pragma unroll
    for (int mt = 0; mt < 2; ++mt){
      float rs[4] = {0.f,0.f,0.f,0.f};
      #pragma unroll
      for (int nt = 0; nt < 2; ++nt){
        int k = nt*16 + lq;
        int j = nt*2 + (lq>>3);
        #pragma unroll
        for (int r = 0; r < 4; ++r){
          float p = exp2f(sa[mt][nt][r]*C1 - m_[mt][r]);
          rs[r] += p;
          int qq = mt*16 + lg*4 + r;
          int prow = qq >> 1;
          int slot = (qq&1)*4 + ((j + prow) & 3);
          *(u16*)(Pw + prow*128 + slot*16 + (k&7)*2) = f2bf(p);
        }
      }
      #pragma unroll
      for (int r = 0; r < 4; ++r){
        float v = rs[r];
        v += __shfl_xor(v, 1);
        v += __shfl_xor(v, 2);
        v += __shfl_xor(v, 4);
        v += __shfl_xor(v, 8);
        l_[mt][r] += v;
      }
    }
    u16x8 pa[2];
    #pragma unroll
    for (int mt = 0; mt < 2; ++mt)
      pa[mt] = *(const u16x8*)(Pw + mt*1024 + bvo);
    #pragma unroll
    for (int nf = 0; nf < 16; ++nf){
      u16x8 vf = *(const u16x8*)(vt + nf*1024 + bvo);
      o[0][nf] = MFMA(pa[0], vf, o[0][nf]);
      o[1][nf] = MFMA(pa[1], vf, o[1][nf]);
    }
    __syncthreads();   // prefetched tiles ready; all waves done with cur
    cur ^= 1;
  }
  size_t ob = ((size_t)((sp*4 + b)*HW + qbase))*CD;
  #pragma unroll
  for (int mt = 0; mt < 2; ++mt)
    #pragma unroll
    for (int nf = 0; nf < 16; ++nf){
      int c = nf*16 + lq;
      #pragma unroll
      for (int r = 0; r < 4; ++r){
        int qq = mt*16 + lg*4 + r;
        Opart[ob + (size_t)qq*CD + c] = f2bf(o[mt][nf][r]);
      }
    }
  if (lq == 0){
    #pragma unroll
    for (int mt = 0; mt < 2; ++mt)
      #pragma unroll
      for (int r = 0; r < 4; ++r){
        int qg = qbase + mt*16 + lg*4 + r;
        ml[(size_t)(sp*4 + b)*HW + qg] = make_float2(m_[mt][r], l_[mt][r]);
      }
  }
}

// ---------------- kernel 4: combine key-splits -> Opm (bf16, pixel-major) ---
__global__ void k_comb(const u16* __restrict__ Opart, const float2* __restrict__ ml,
                       u16* __restrict__ Opm){
  int b = blockIdx.y;
  int q = blockIdx.x*8 + (threadIdx.x >> 5);
  int c0 = (threadIdx.x & 31)*8;
  float2 e[NSP];
  float m = -3.0e38f;
  #pragma unroll
  for (int s = 0; s < NSP; ++s){
    e[s] = ml[(size_t)(s*4 + b)*HW + q];
    m = fmaxf(m, e[s].x);
  }
  float w[NSP], den = 0.f;
  #pragma unroll
  for (int s = 0; s < NSP; ++s){
    w[s] = exp2f(e[s].x - m);
    den += e[s].y * w[s];
  }
  float inv = 1.0f / den;
  float sum[8] = {};
  #pragma unroll
  for (int s = 0; s < NSP; ++s){
    u16x8 v = *(const u16x8*)(Opart + ((size_t)((s*4 + b)*HW) + q)*CD + c0);
    float ws = w[s];
    #pragma unroll
    for (int t = 0; t < 8; ++t)
      sum[t] += bf2f(v[t]) * ws;
  }
  u16x8 o;
  #pragma unroll
  for (int t = 0; t < 8; ++t)
    o[t] = f2bf(sum[t]*inv);
  *(u16x8*)(Opm + ((size_t)(b*HW) + q)*CD + c0) = o;
}

// ---------------- kernel 5: output projection + bias + residual -------------
__global__ __launch_bounds__(256,2) void k_proj(const u16* __restrict__ Opm, const u16* __restrict__ Wp,
    const float* __restrict__ bp, const float* __restrict__ x, float* __restrict__ out){
  int b = blockIdx.y, pbase = blockIdx.x*64;
  int tid = threadIdx.x, lane = tid & 63, wave = tid >> 6;
  int lq = lane & 15, lg = lane >> 4;
  int nbase = wave*64;
  f32x4 acc[4][4] = {};
  #pragma unroll
  for (int kk = 0; kk < 8; ++kk){
    u16x8 af[4], bf[4];
    #pragma unroll
    for (int m = 0; m < 4; ++m)
      af[m] = *(const u16x8*)(Opm + ((size_t)(b*HW + pbase + m*16 + lq))*CD + kk*32 + lg*8);
    #pragma unroll
    for (int n = 0; n < 4; ++n)
      bf[n] = *(const u16x8*)(Wp + (size_t)(nbase + n*16 + lq)*CD + kk*32 + lg*8);
    #pragma unroll
    for (int m = 0; m < 4; ++m)
      #pragma unroll
      for (int n = 0; n < 4; ++n)
        acc[m][n] = MFMA(af[m], bf[n], acc[m][n]);
  }
  #pragma unroll
  for (int m = 0; m < 4; ++m)
    #pragma unroll
    for (int n = 0; n < 4; ++n){
      int d = nbase + n*16 + lq;
      int p0 = pbase + m*16 + lg*4;
      size_t base = (size_t)(b*CD + d)*HW + p0;
      float bb = bp[d];
      float4 res = *(const float4*)(x + base);
      float4 ov;
      ov.x = acc[m][n][0] + bb + res.x;
      ov.y = acc[m][n][1] + bb + res.y;
      ov.z = acc[m][n][2] + bb + res.z;
      ov.w = acc[m][n][3] + bb + res.w;
      *(float4*)(out + base) = ov;
    }
}

extern "C" void kernel_launch(void* const* d_in, const int* in_sizes, int n_in,
                              void* d_out, int out_size, void* d_ws, size_t ws_size,
                              hipStream_t stream){
  const float* x     = (const float*)d_in[0];
  const float* gamma = (const float*)d_in[1];
  const float* beta  = (const float*)d_in[2];
  const float* wq    = (const float*)d_in[3];
  const float* bq    = (const float*)d_in[4];
  const float* wk    = (const float*)d_in[5];
  const float* bk    = (const float*)d_in[6];
  const float* wv    = (const float*)d_in[7];
  const float* bv    = (const float*)d_in[8];
  const float* wp    = (const float*)d_in[9];
  const float* bp    = (const float*)d_in[10];
  float* out = (float*)d_out;

  char* ws = (char*)d_ws;
  u16*   xnT   = (u16*)(ws);                                   // 8 MiB
  u16*   Qb    = (u16*)(ws + (8ull<<20));                      // 8 MiB
  u16*   Kb    = (u16*)(ws + (16ull<<20));                     // 8 MiB
  u16*   Vb    = (u16*)(ws + (24ull<<20));                     // 8 MiB
  u16*   Opm   = (u16*)(ws + (32ull<<20));                     // 8 MiB
  u16*   Wbf   = (u16*)(ws + (40ull<<20));                     // 512 KiB
  float2* mlb  = (float2*)(ws + (40ull<<20) + (512ull<<10));   // 512 KiB
  u16*   Opart = (u16*)(ws + (41ull<<20));                     // 32 MiB (bf16)

  hipFuncSetAttribute((const void*)k_attn, hipFuncAttributeMaxDynamicSharedMemorySize, 73728);

  k_prep<<<dim3(64,4), 256, 0, stream>>>(wq, wk, wv, wp, Wbf);
  k_gn  <<<dim3(8,4),  256, 0, stream>>>(x, gamma, beta, xnT);
  k_qkv <<<dim3(64,4,3), 256, 0, stream>>>(xnT, Wbf, bq, bk, bv, Qb, Kb, Vb);
  k_attn<<<dim3(32,NSP,4), 256, 73728, stream>>>(Qb, Kb, Vb, Opart, mlb);
  k_comb<<<dim3(512,4), 256, 0, stream>>>(Opart, mlb, Opm);
  k_proj<<<dim3(64,4), 256, 0, stream>>>(Opm, Wbf + 3*65536, bp, x, out);
}

// Round 6
// 265.297 us; speedup vs baseline: 3.2629x; 3.2629x over previous
//
#include <hip/hip_runtime.h>

#define HW 4096
#define CD 256
#define KB 32           /* keys per KV-iter */
#define NKB 32          /* 32 x 32 = 1024 keys per split */
#define NSP 4
#define C1 0.09016844f  /* (1/16) * log2(e) */

typedef __bf16 bf16x8v __attribute__((ext_vector_type(8)));
typedef float f32x4 __attribute__((ext_vector_type(4)));
typedef unsigned short u16;
typedef u16 u16x4 __attribute__((ext_vector_type(4)));
typedef u16 u16x8 __attribute__((ext_vector_type(8)));

static __device__ __forceinline__ u16 f2bf(float f){
  __bf16 h = (__bf16)f;
  return __builtin_bit_cast(u16, h);
}
static __device__ __forceinline__ float bf2f(u16 v){
  unsigned u = ((unsigned)v) << 16;
  return __builtin_bit_cast(float, u);
}

static __device__ __forceinline__ f32x4 MFMA(u16x8 a, u16x8 b, f32x4 c){
  return __builtin_amdgcn_mfma_f32_16x16x32_bf16(
      __builtin_bit_cast(bf16x8v, a), __builtin_bit_cast(bf16x8v, b), c, 0, 0, 0);
}

#define GLL16(gsrc, ldst) __builtin_amdgcn_global_load_lds( \
    (const __attribute__((address_space(1))) void*)(gsrc),  \
    (__attribute__((address_space(3))) void*)(ldst), 16, 0, 0)

// ---------------- kernel 0: weights fp32 -> bf16 (layout kept [out][in]) ----
__global__ void k_prep(const float* __restrict__ wq, const float* __restrict__ wk,
                       const float* __restrict__ wv, const float* __restrict__ wp,
                       u16* __restrict__ Wbf){
  int z = blockIdx.y;
  const float* src = (z==0)?wq:(z==1)?wk:(z==2)?wv:wp;
  int i = (blockIdx.x*256 + threadIdx.x)*4;
  float4 v = *(const float4*)(src + i);
  u16x4 o = { f2bf(v.x), f2bf(v.y), f2bf(v.z), f2bf(v.w) };
  *(u16x4*)(Wbf + z*65536 + i) = o;
}

// ---------------- kernel 1: groupnorm, write xn pixel-major bf16 ------------
__global__ void k_gn(const float* __restrict__ x, const float* __restrict__ gamma,
                     const float* __restrict__ beta, u16* __restrict__ xnT){
  int g = blockIdx.x, b = blockIdx.y;
  int tid = threadIdx.x;
  const float* xp = x + ((size_t)(b*CD) + g*32) * HW;
  float s0 = 0.f, s1 = 0.f;
  for (int i = tid*4; i < 32*HW; i += 1024){
    float4 v = *(const float4*)(xp + i);
    s0 += v.x + v.y + v.z + v.w;
    s1 += v.x*v.x + v.y*v.y + v.z*v.z + v.w*v.w;
  }
  #pragma unroll
  for (int m = 1; m < 64; m <<= 1){ s0 += __shfl_xor(s0, m); s1 += __shfl_xor(s1, m); }
  __shared__ float red[8];
  __shared__ float stats[2];
  int lane = tid & 63, wave = tid >> 6;
  if (lane == 0){ red[wave] = s0; red[4+wave] = s1; }
  __syncthreads();
  if (tid == 0){
    float t0 = red[0]+red[1]+red[2]+red[3];
    float t1 = red[4]+red[5]+red[6]+red[7];
    float inv_n = 1.0f/(32.0f*HW);
    float mean = t0*inv_n;
    float var = t1*inv_n - mean*mean;
    stats[0] = mean;
    stats[1] = rsqrtf(var + 1e-5f);
  }
  __syncthreads();
  float mean = stats[0], rstd = stats[1];
  int pl = tid >> 2, c8 = (tid & 3)*8;
  float av[8], bv_[8];
  #pragma unroll
  for (int e = 0; e < 8; ++e){
    int c = g*32 + c8 + e;
    float a = rstd * gamma[c];
    av[e] = a;
    bv_[e] = beta[c] - mean*a;
  }
  const float* xb = x + (size_t)(b*CD + g*32 + c8)*HW;
  for (int it = 0; it < 64; ++it){
    int p = it*64 + pl;
    u16x8 o;
    #pragma unroll
    for (int e = 0; e < 8; ++e){
      float v = xb[(size_t)e*HW + p];
      o[e] = f2bf(v*av[e] + bv_[e]);
    }
    *(u16x8*)(xnT + ((size_t)(b*HW) + p)*CD + g*32 + c8) = o;
  }
}

// ---------------- kernel 2: QKV projection GEMM -----------------------------
// Q,K pixel-major [b][p][c]; V channel-major [b][c][p]
__global__ __launch_bounds__(256,2) void k_qkv(const u16* __restrict__ xnT, const u16* __restrict__ Wbf,
    const float* __restrict__ bq, const float* __restrict__ bk, const float* __restrict__ bv,
    u16* __restrict__ Q, u16* __restrict__ K, u16* __restrict__ V){
  __shared__ u16 tile[4][4096];
  int z = blockIdx.z, b = blockIdx.y, pbase = blockIdx.x*64;
  int tid = threadIdx.x, lane = tid & 63, wave = tid >> 6;
  int lq = lane & 15, lg = lane >> 4;
  const u16* W = Wbf + z*65536;
  const float* bias = (z==0)?bq:(z==1)?bk:bv;
  int nbase = wave*64;
  f32x4 acc[4][4] = {};
  #pragma unroll
  for (int kk = 0; kk < 8; ++kk){
    u16x8 af[4], bf[4];
    #pragma unroll
    for (int m = 0; m < 4; ++m)
      af[m] = *(const u16x8*)(xnT + ((size_t)(b*HW + pbase + m*16 + lq))*CD + kk*32 + lg*8);
    #pragma unroll
    for (int n = 0; n < 4; ++n)
      bf[n] = *(const u16x8*)(W + (size_t)(nbase + n*16 + lq)*CD + kk*32 + lg*8);
    #pragma unroll
    for (int m = 0; m < 4; ++m)
      #pragma unroll
      for (int n = 0; n < 4; ++n)
        acc[m][n] = MFMA(af[m], bf[n], acc[m][n]);
  }
  #pragma unroll
  for (int n = 0; n < 4; ++n){
    float bb = bias[nbase + n*16 + lq];
    #pragma unroll
    for (int m = 0; m < 4; ++m){
      acc[m][n][0] += bb; acc[m][n][1] += bb; acc[m][n][2] += bb; acc[m][n][3] += bb;
    }
  }
  if (z == 2){
    #pragma unroll
    for (int m = 0; m < 4; ++m)
      #pragma unroll
      for (int n = 0; n < 4; ++n){
        int d = nbase + n*16 + lq;
        int p0 = pbase + m*16 + lg*4;
        u16x4 o = { f2bf(acc[m][n][0]), f2bf(acc[m][n][1]), f2bf(acc[m][n][2]), f2bf(acc[m][n][3]) };
        *(u16x4*)(V + (size_t)(b*CD + d)*HW + p0) = o;
      }
  } else {
    u16* dst = (z==0)?Q:K;
    u16* tl = tile[wave];
    #pragma unroll
    for (int m = 0; m < 4; ++m)
      #pragma unroll
      for (int n = 0; n < 4; ++n)
        #pragma unroll
        for (int r = 0; r < 4; ++r){
          int row = m*16 + lg*4 + r;
          int col = n*16 + lq;
          tl[row*64 + ((((col>>3) + row) & 7)<<3) + (col & 7)] = f2bf(acc[m][n][r]);
        }
    #pragma unroll
    for (int j = 0; j < 8; ++j){
      int idx = j*64 + lane;
      int row = idx >> 3, ch = idx & 7;
      u16x8 v = *(const u16x8*)(tl + row*64 + (((ch + row)&7)<<3));
      *(u16x8*)(dst + ((size_t)(b*HW + pbase + row))*CD + nbase + ch*8) = v;
    }
  }
}

// ---------------- kernel 3: flash attention (key-split 4) -------------------
// 16 q/WAVE (the r1-r5 lesson: 32q/wave needs ~384 regs -> hard 1 wave/SIMD;
// forced caps spill 1.6GB. 16q: acc 64 + Q 32 + ~80 working ~ 175 regs ->
// fits (256,2) budget with slack -> 2 waves/SIMD, zero spill).
// grid (64 qtiles, 4 splits, 4 b) = 1024 blocks; 4 waves x 16 q = 64 q/block.
// LDS 68KB: K dbuf 2x16K | V dbuf 2x16K | P 4x1K -> 2 blocks/CU = 8 waves/CU.
// K rows XOR-swizzled; V/P paired-row (128B) swizzle (r5: 0 bank conflicts).
__global__ __launch_bounds__(256,2) void k_attn(const u16* __restrict__ Q, const u16* __restrict__ K,
    const u16* __restrict__ V, u16* __restrict__ Opart, float2* __restrict__ ml){
  extern __shared__ char smem[];
  int tid = threadIdx.x, lane = tid & 63, wave = tid >> 6;
  int lq = lane & 15, lg = lane >> 4;
  int qt = blockIdx.x, sp = blockIdx.y, b = blockIdx.z;
  int qbase = qt*64 + wave*16;
  int key0 = sp*(NKB*KB);

  // staging source offsets (inverse of the LDS read swizzles; LDS dest linear)
  int ke[4], ve[4];
  #pragma unroll
  for (int i = 0; i < 4; ++i){
    int G = i*256 + tid;            // chunk 0..1023 of 16B per 16KB tile
    int kr = G >> 5;                // K row (32 rows x 512B)
    ke[i] = kr*CD + (((G & 31) ^ kr) & 31)*8;
    int vrow = G >> 3;              // V d-pair row (128 rows x 128B)
    int p = (G >> 2) & 1;           // d parity
    int j = ((G & 3) - vrow) & 3;   // stored k-chunk
    ve[i] = (vrow*2 + p)*HW + j*8;
  }
  // V/P read offset within a 128B paired row (constant per lane)
  int bvo = (lq>>1)*128 + (((lq&1)*4 + ((lg + (lq>>1)) & 3)))*16;

  u16x8 qa[8];
  #pragma unroll
  for (int cc = 0; cc < 8; ++cc)
    qa[cc] = *(const u16x8*)(Q + ((size_t)(b*HW + qbase + lq))*CD + cc*32 + lg*8);

  f32x4 o[16] = {};
  float m_[4], l_[4];
  #pragma unroll
  for (int r = 0; r < 4; ++r){ m_[r] = -3.0e38f; l_[r] = 0.f; }

  const u16* Kb = K + (size_t)(b*HW + key0)*CD;
  const u16* Vb = V + (size_t)(b*CD)*HW + key0;
  char* Pw = smem + 65536 + wave*1024;

  {
    char* kd = smem; char* vd = smem + 32768;
    #pragma unroll
    for (int i = 0; i < 4; ++i){
      GLL16(Kb + ke[i], kd + i*4096 + wave*1024);
      GLL16(Vb + ve[i], vd + i*4096 + wave*1024);
    }
  }
  __syncthreads();
  int cur = 0;
  for (int kb = 0; kb < NKB; ++kb){
    if (kb + 1 < NKB){
      char* kd = smem + (cur^1)*16384;
      char* vd = smem + 32768 + (cur^1)*16384;
      const u16* kg = Kb + (size_t)(kb+1)*KB*CD;
      const u16* vg = Vb + (kb+1)*KB;
      #pragma unroll
      for (int i = 0; i < 4; ++i){
        GLL16(kg + ke[i], kd + i*4096 + wave*1024);
        GLL16(vg + ve[i], vd + i*4096 + wave*1024);
      }
    }
    const char* kt = smem + cur*16384;
    const char* vt = smem + 32768 + cur*16384;

    f32x4 sa[2];
    sa[0] = (f32x4){0.f,0.f,0.f,0.f};
    sa[1] = (f32x4){0.f,0.f,0.f,0.f};
    #pragma unroll
    for (int nt = 0; nt < 2; ++nt){
      int row = nt*16 + lq;
      #pragma unroll
      for (int cc = 0; cc < 8; ++cc){
        int ch = cc*4 + lg;
        u16x8 kf = *(const u16x8*)(kt + row*512 + (((ch ^ row) & 31) << 4));
        sa[nt] = MFMA(qa[cc], kf, sa[nt]);
      }
    }
    float mx[4];
    #pragma unroll
    for (int r = 0; r < 4; ++r){
      float v = fmaxf(sa[0][r], sa[1][r]) * C1;
      v = fmaxf(v, __shfl_xor(v, 1));
      v = fmaxf(v, __shfl_xor(v, 2));
      v = fmaxf(v, __shfl_xor(v, 4));
      v = fmaxf(v, __shfl_xor(v, 8));
      mx[r] = v;
    }
    int okf = 1;
    #pragma unroll
    for (int r = 0; r < 4; ++r)
      okf &= (mx[r] <= m_[r] + 8.0f) ? 1 : 0;
    if (!__all(okf)){
      #pragma unroll
      for (int r = 0; r < 4; ++r){
        float nm = fmaxf(m_[r], mx[r]);
        float corr = exp2f(m_[r] - nm);
        m_[r] = nm;
        l_[r] *= corr;
        #pragma unroll
        for (int nf = 0; nf < 16; ++nf)
          o[nf][r] *= corr;
      }
    }
    {
      float rs[4] = {0.f,0.f,0.f,0.f};
      #pragma unroll
      for (int nt = 0; nt < 2; ++nt){
        int k = nt*16 + lq;
        int j = nt*2 + (lq>>3);
        #pragma unroll
        for (int r = 0; r < 4; ++r){
          float p = exp2f(sa[nt][r]*C1 - m_[r]);
          rs[r] += p;
          int qq = lg*4 + r;
          int prow = qq >> 1;
          int slot = (qq&1)*4 + ((j + prow) & 3);
          *(u16*)(Pw + prow*128 + slot*16 + (k&7)*2) = f2bf(p);
        }
      }
      #pragma unroll
      for (int r = 0; r < 4; ++r){
        float v = rs[r];
        v += __shfl_xor(v, 1);
        v += __shfl_xor(v, 2);
        v += __shfl_xor(v, 4);
        v += __shfl_xor(v, 8);
        l_[r] += v;
      }
    }
    u16x8 pa = *(const u16x8*)(Pw + bvo);
    #pragma unroll
    for (int nf = 0; nf < 16; ++nf){
      u16x8 vf = *(const u16x8*)(vt + nf*1024 + bvo);
      o[nf] = MFMA(pa, vf, o[nf]);
    }
    __syncthreads();   // prefetched tiles ready; all waves done with cur
    cur ^= 1;
  }
  size_t ob = ((size_t)((sp*4 + b)*HW + qbase))*CD;
  #pragma unroll
  for (int nf = 0; nf < 16; ++nf){
    int c = nf*16 + lq;
    #pragma unroll
    for (int r = 0; r < 4; ++r){
      int qq = lg*4 + r;
      Opart[ob + (size_t)qq*CD + c] = f2bf(o[nf][r]);
    }
  }
  if (lq == 0){
    #pragma unroll
    for (int r = 0; r < 4; ++r){
      int qg = qbase + lg*4 + r;
      ml[(size_t)(sp*4 + b)*HW + qg] = make_float2(m_[r], l_[r]);
    }
  }
}

// ---------------- kernel 4: combine key-splits -> Opm (bf16, pixel-major) ---
__global__ void k_comb(const u16* __restrict__ Opart, const float2* __restrict__ ml,
                       u16* __restrict__ Opm){
  int b = blockIdx.y;
  int q = blockIdx.x*8 + (threadIdx.x >> 5);
  int c0 = (threadIdx.x & 31)*8;
  float2 e[NSP];
  float m = -3.0e38f;
  #pragma unroll
  for (int s = 0; s < NSP; ++s){
    e[s] = ml[(size_t)(s*4 + b)*HW + q];
    m = fmaxf(m, e[s].x);
  }
  float w[NSP], den = 0.f;
  #pragma unroll
  for (int s = 0; s < NSP; ++s){
    w[s] = exp2f(e[s].x - m);
    den += e[s].y * w[s];
  }
  float inv = 1.0f / den;
  float sum[8] = {};
  #pragma unroll
  for (int s = 0; s < NSP; ++s){
    u16x8 v = *(const u16x8*)(Opart + ((size_t)((s*4 + b)*HW) + q)*CD + c0);
    float ws = w[s];
    #pragma unroll
    for (int t = 0; t < 8; ++t)
      sum[t] += bf2f(v[t]) * ws;
  }
  u16x8 o;
  #pragma unroll
  for (int t = 0; t < 8; ++t)
    o[t] = f2bf(sum[t]*inv);
  *(u16x8*)(Opm + ((size_t)(b*HW) + q)*CD + c0) = o;
}

// ---------------- kernel 5: output projection + bias + residual -------------
__global__ __launch_bounds__(256,2) void k_proj(const u16* __restrict__ Opm, const u16* __restrict__ Wp,
    const float* __restrict__ bp, const float* __restrict__ x, float* __restrict__ out){
  int b = blockIdx.y, pbase = blockIdx.x*64;
  int tid = threadIdx.x, lane = tid & 63, wave = tid >> 6;
  int lq = lane & 15, lg = lane >> 4;
  int nbase = wave*64;
  f32x4 acc[4][4] = {};
  #pragma unroll
  for (int kk = 0; kk < 8; ++kk){
    u16x8 af[4], bf[4];
    #pragma unroll
    for (int m = 0; m < 4; ++m)
      af[m] = *(const u16x8*)(Opm + ((size_t)(b*HW + pbase + m*16 + lq))*CD + kk*32 + lg*8);
    #pragma unroll
    for (int n = 0; n < 4; ++n)
      bf[n] = *(const u16x8*)(Wp + (size_t)(nbase + n*16 + lq)*CD + kk*32 + lg*8);
    #pragma unroll
    for (int m = 0; m < 4; ++m)
      #pragma unroll
      for (int n = 0; n < 4; ++n)
        acc[m][n] = MFMA(af[m], bf[n], acc[m][n]);
  }
  #pragma unroll
  for (int m = 0; m < 4; ++m)
    #pragma unroll
    for (int n = 0; n < 4; ++n){
      int d = nbase + n*16 + lq;
      int p0 = pbase + m*16 + lg*4;
      size_t base = (size_t)(b*CD + d)*HW + p0;
      float bb = bp[d];
      float4 res = *(const float4*)(x + base);
      float4 ov;
      ov.x = acc[m][n][0] + bb + res.x;
      ov.y = acc[m][n][1] + bb + res.y;
      ov.z = acc[m][n][2] + bb + res.z;
      ov.w = acc[m][n][3] + bb + res.w;
      *(float4*)(out + base) = ov;
    }
}

extern "C" void kernel_launch(void* const* d_in, const int* in_sizes, int n_in,
                              void* d_out, int out_size, void* d_ws, size_t ws_size,
                              hipStream_t stream){
  const float* x     = (const float*)d_in[0];
  const float* gamma = (const float*)d_in[1];
  const float* beta  = (const float*)d_in[2];
  const float* wq    = (const float*)d_in[3];
  const float* bq    = (const float*)d_in[4];
  const float* wk    = (const float*)d_in[5];
  const float* bk    = (const float*)d_in[6];
  const float* wv    = (const float*)d_in[7];
  const float* bv    = (const float*)d_in[8];
  const float* wp    = (const float*)d_in[9];
  const float* bp    = (const float*)d_in[10];
  float* out = (float*)d_out;

  char* ws = (char*)d_ws;
  u16*   xnT   = (u16*)(ws);                                   // 8 MiB
  u16*   Qb    = (u16*)(ws + (8ull<<20));                      // 8 MiB
  u16*   Kb    = (u16*)(ws + (16ull<<20));                     // 8 MiB
  u16*   Vb    = (u16*)(ws + (24ull<<20));                     // 8 MiB
  u16*   Opm   = (u16*)(ws + (32ull<<20));                     // 8 MiB
  u16*   Wbf   = (u16*)(ws + (40ull<<20));                     // 512 KiB
  float2* mlb  = (float2*)(ws + (40ull<<20) + (512ull<<10));   // 512 KiB
  u16*   Opart = (u16*)(ws + (41ull<<20));                     // 32 MiB (bf16)

  hipFuncSetAttribute((const void*)k_attn, hipFuncAttributeMaxDynamicSharedMemorySize, 69632);

  k_prep<<<dim3(64,4), 256, 0, stream>>>(wq, wk, wv, wp, Wbf);
  k_gn  <<<dim3(8,4),  256, 0, stream>>>(x, gamma, beta, xnT);
  k_qkv <<<dim3(64,4,3), 256, 0, stream>>>(xnT, Wbf, bq, bk, bv, Qb, Kb, Vb);
  k_attn<<<dim3(64,NSP,4), 256, 69632, stream>>>(Qb, Kb, Vb, Opart, mlb);
  k_comb<<<dim3(512,4), 256, 0, stream>>>(Opart, mlb, Opm);
  k_proj<<<dim3(64,4), 256, 0, stream>>>(Opm, Wbf + 3*65536, bp, x, out);
}